// Round 1
// baseline (2995.819 us; speedup 1.0000x reference)
//
#include <hip/hip_runtime.h>
#include <math.h>

#define NROW 8192
#define DDIM 128
#define CAP 65536
#define NITERS 100

struct Entry { int i, j; float s, t; };

// ws layout (bytes):
// 0      : x2  float[NROW]            (32768)
// 32768  : y2  float[NROW]            (32768)
// 65536  : counts int[3]              (pad to 65600)
// 65600  : accum double[3][264]       { [0]=Su [1]=Sv [2]=Sux2 [3]=Svy2 [4]=Ssp [5..7]=pad [8..135]=P [136..263]=Q }
// 71936  : lists Entry[3][CAP]        (3 MiB)

__global__ void init_k(int* counts, double* accum) {
    int t = threadIdx.x;
    if (t < 3) counts[t] = 0;
    for (int i = t; i < 3 * 264; i += 256) accum[i] = 0.0;
}

__global__ void norms_k(const float* __restrict__ X, const float* __restrict__ Y,
                        float* __restrict__ x2, float* __restrict__ y2) {
    int gw = (blockIdx.x * blockDim.x + threadIdx.x) >> 6;
    int lane = threadIdx.x & 63;
    if (gw >= 2 * NROW) return;
    const float* M = (gw < NROW) ? X : Y;
    float* out = (gw < NROW) ? x2 : y2;
    int r = (gw < NROW) ? gw : gw - NROW;
    float2 v = *(const float2*)(M + (size_t)r * DDIM + lane * 2);
    float s = v.x * v.x + v.y * v.y;
    for (int o = 32; o; o >>= 1) s += __shfl_down(s, o, 64);
    if (lane == 0) out[r] = s;
}

// prune: 8-dim partial distance lower bound; push candidate (i,j) pairs
__global__ __launch_bounds__(256) void prune_k(const float* __restrict__ X,
                                               const float* __restrict__ Y,
                                               int* counts, Entry* lists) {
    int p = blockIdx.y;
    const float* A = (p == 2) ? Y : X;
    const float* B = (p == 0) ? Y : ((p == 1) ? X : Y);
    int i0 = blockIdx.x * 128;
    __shared__ float A9[128][9];
    int t = threadIdx.x;
    {
        int r = t >> 1, c = (t & 1) * 4;
        float4 v = *(const float4*)(A + (size_t)(i0 + r) * DDIM + c);
        A9[r][c + 0] = v.x; A9[r][c + 1] = v.y; A9[r][c + 2] = v.z; A9[r][c + 3] = v.w;
    }
    __syncthreads();
    if (t < 128) {
        float pn = 0.f;
        #pragma unroll
        for (int k = 0; k < 8; k++) pn += A9[t][k] * A9[t][k];
        A9[t][8] = pn;
    }
    __syncthreads();
    Entry* list = lists + (size_t)p * CAP;
    for (int jc = 0; jc < 8; jc++) {
        int jbase = jc * 1024;
        float b[4][8]; float pnb[4];
        #pragma unroll
        for (int k = 0; k < 4; k++) {
            int j = jbase + t + 256 * k;
            float4 v0 = *(const float4*)(B + (size_t)j * DDIM);
            float4 v1 = *(const float4*)(B + (size_t)j * DDIM + 4);
            b[k][0] = v0.x; b[k][1] = v0.y; b[k][2] = v0.z; b[k][3] = v0.w;
            b[k][4] = v1.x; b[k][5] = v1.y; b[k][6] = v1.z; b[k][7] = v1.w;
            float pn = 0.f;
            #pragma unroll
            for (int m = 0; m < 8; m++) pn += b[k][m] * b[k][m];
            pnb[k] = pn;
        }
        for (int r = 0; r < 128; r++) {
            float a[8];
            #pragma unroll
            for (int m = 0; m < 8; m++) a[m] = A9[r][m];
            float pna = A9[r][8];
            #pragma unroll
            for (int k = 0; k < 4; k++) {
                float dot = 0.f;
                #pragma unroll
                for (int m = 0; m < 8; m++) dot = fmaf(a[m], b[k][m], dot);
                float d = fmaf(-2.f, dot, pna + pnb[k]);
                if (d < 0.25f) {
                    int idx = atomicAdd(&counts[p], 1);
                    if (idx < CAP) { list[idx].i = i0 + r; list[idx].j = jbase + t + 256 * k; }
                }
            }
        }
    }
}

// exact: full 128-dim distance for survivors; compute S value and cost correction
__global__ __launch_bounds__(256) void exact_k(const float* __restrict__ X,
                                               const float* __restrict__ Y,
                                               const float* __restrict__ x2,
                                               const float* __restrict__ y2,
                                               const int* counts, Entry* lists) {
    int p = blockIdx.y;
    const float* A = (p == 2) ? Y : X;
    const float* B = (p == 0) ? Y : ((p == 1) ? X : Y);
    const float* na = (p == 2) ? y2 : x2;
    const float* nb = (p == 0) ? y2 : ((p == 1) ? x2 : y2);
    int cnt = counts[p]; if (cnt > CAP) cnt = CAP;
    Entry* list = lists + (size_t)p * CAP;
    int w = (blockIdx.x * 256 + threadIdx.x) >> 6;  // 2048 blocks * 4 waves = 8192 slots
    int lane = threadIdx.x & 63;
    for (int e = w; e < cnt; e += 8192) {
        int i = list[e].i, j = list[e].j;
        const float* ar = A + (size_t)i * DDIM;
        const float* br = B + (size_t)j * DDIM;
        float dot = ar[lane] * br[lane] + ar[lane + 64] * br[lane + 64];
        for (int o = 32; o; o >>= 1) dot += __shfl_down(dot, o, 64);
        if (lane == 0) {
            float raw = na[i] + nb[j] - 2.0f * dot;
            float C = fmaxf(raw, 0.0f);
            float sc = fmaxf(-C * 100.0f, -50.0f);   // clip(-C/eps, -50, 0), C>=0
            float K = fmaxf(expf(sc), 1e-8f);
            list[e].s = K - 1e-8f;
            list[e].t = K * C - 1e-8f * raw;
        }
    }
}

// 100 Sinkhorn iterations per pair (one block each), then epilogue partial sums
__global__ __launch_bounds__(1024) void sink_k(const float* __restrict__ X,
                                               const float* __restrict__ Y,
                                               const float* __restrict__ x2,
                                               const float* __restrict__ y2,
                                               const int* counts, const Entry* __restrict__ lists,
                                               double* accum) {
    int p = blockIdx.x;
    const float* A = (p == 2) ? Y : X;
    const float* B = (p == 0) ? Y : ((p == 1) ? X : Y);
    const float* na = (p == 2) ? y2 : x2;
    const float* nb = (p == 0) ? y2 : ((p == 1) ? x2 : y2);
    const Entry* list = lists + (size_t)p * CAP;
    int cnt = counts[p]; if (cnt > CAP) cnt = CAP;
    double* acc = accum + (size_t)p * 264;

    __shared__ float u_s[NROW];
    __shared__ float v_s[NROW];
    int t = threadIdx.x;
    int wid = t >> 6, lane = t & 63;
    const float AC = 1.0f / 8192.0f;

    for (int i = t; i < NROW; i += 1024) { u_s[i] = 1.0f; v_s[i] = 1.0f; }
    __syncthreads();

    for (int it = 0; it < NITERS; it++) {
        // ---- phase A: u = a / max(1e-8*sum(v) + S@v, 1e-8) ----
        {
            float sv = 0.f;
            for (int i = t; i < NROW; i += 1024) sv += v_s[i];
            for (int o = 32; o; o >>= 1) sv += __shfl_down(sv, o, 64);
            if (lane == 0) u_s[wid] = sv;   // u_s (old u) is dead: scratch
            __syncthreads();
            if (t < 64) {
                float s2 = (t < 16) ? u_s[t] : 0.f;
                for (int o = 8; o; o >>= 1) s2 += __shfl_down(s2, o, 64);
                if (t == 0) u_s[0] = s2;
            }
            __syncthreads();
            float sum_v = u_s[0];
            __syncthreads();
            for (int i = t; i < NROW; i += 1024) u_s[i] = 1e-8f * sum_v;
            __syncthreads();
            for (int e = t; e < cnt; e += 1024)
                atomicAdd(&u_s[list[e].i], list[e].s * v_s[list[e].j]);
            __syncthreads();
            for (int i = t; i < NROW; i += 1024) u_s[i] = AC / fmaxf(u_s[i], 1e-8f);
            __syncthreads();
        }
        // ---- phase B: v = b / max(1e-8*sum(u) + S^T@u, 1e-8) ----
        {
            float su = 0.f;
            for (int i = t; i < NROW; i += 1024) su += u_s[i];
            for (int o = 32; o; o >>= 1) su += __shfl_down(su, o, 64);
            if (lane == 0) v_s[wid] = su;   // v_s (old v) is dead: scratch
            __syncthreads();
            if (t < 64) {
                float s2 = (t < 16) ? v_s[t] : 0.f;
                for (int o = 8; o; o >>= 1) s2 += __shfl_down(s2, o, 64);
                if (t == 0) v_s[0] = s2;
            }
            __syncthreads();
            float sum_u = v_s[0];
            __syncthreads();
            for (int i = t; i < NROW; i += 1024) v_s[i] = 1e-8f * sum_u;
            __syncthreads();
            for (int e = t; e < cnt; e += 1024)
                atomicAdd(&v_s[list[e].j], list[e].s * u_s[list[e].i]);
            __syncthreads();
            for (int i = t; i < NROW; i += 1024) v_s[i] = AC / fmaxf(v_s[i], 1e-8f);
            __syncthreads();
        }
    }

    // ---- epilogue: partial sums into global accumulators (init_k zeroed them) ----
    {
        double pSu = 0, pSv = 0, pSux2 = 0, pSvy2 = 0;
        for (int i = t; i < NROW; i += 1024) {
            double ui = u_s[i], vi = v_s[i];
            pSu += ui; pSv += vi;
            pSux2 += ui * (double)na[i];
            pSvy2 += vi * (double)nb[i];
        }
        for (int o = 32; o; o >>= 1) {
            pSu += __shfl_down(pSu, o, 64);   pSv += __shfl_down(pSv, o, 64);
            pSux2 += __shfl_down(pSux2, o, 64); pSvy2 += __shfl_down(pSvy2, o, 64);
        }
        if (lane == 0) {
            atomicAdd(&acc[0], pSu); atomicAdd(&acc[1], pSv);
            atomicAdd(&acc[2], pSux2); atomicAdd(&acc[3], pSvy2);
        }
    }
    // weighted feature sums P[d] = sum_i u_i*A[i,d], Q[d] = sum_j v_j*B[j,d]
    {
        int dq = (t & 31) * 4, g = t >> 5;  // 32 row-groups, 4 dims/thread
        double pp[4] = {0, 0, 0, 0}, qq[4] = {0, 0, 0, 0};
        for (int i = g; i < NROW; i += 32) {
            float4 av = *(const float4*)(A + (size_t)i * DDIM + dq);
            float us = u_s[i];
            pp[0] += (double)us * av.x; pp[1] += (double)us * av.y;
            pp[2] += (double)us * av.z; pp[3] += (double)us * av.w;
            float4 bv = *(const float4*)(B + (size_t)i * DDIM + dq);
            float vs = v_s[i];
            qq[0] += (double)vs * bv.x; qq[1] += (double)vs * bv.y;
            qq[2] += (double)vs * bv.z; qq[3] += (double)vs * bv.w;
        }
        #pragma unroll
        for (int m = 0; m < 4; m++) {
            atomicAdd(&acc[8 + dq + m], pp[m]);
            atomicAdd(&acc[136 + dq + m], qq[m]);
        }
    }
    // sparse cost correction
    {
        double sp = 0;
        for (int e = t; e < cnt; e += 1024)
            sp += (double)u_s[list[e].i] * (double)v_s[list[e].j] * (double)list[e].t;
        for (int o = 32; o; o >>= 1) sp += __shfl_down(sp, o, 64);
        if (lane == 0) atomicAdd(&acc[4], sp);
    }
}

__global__ void combine_k(const double* __restrict__ accum, float* __restrict__ out) {
    int t = threadIdx.x;  // 64 threads
    __shared__ double costs[3];
    for (int p = 0; p < 3; p++) {
        const double* acc = accum + (size_t)p * 264;
        double part = acc[8 + t] * acc[136 + t] + acc[8 + 64 + t] * acc[136 + 64 + t];
        for (int o = 32; o; o >>= 1) part += __shfl_down(part, o, 64);
        if (t == 0) {
            double F = acc[2] * acc[1] + acc[0] * acc[3] - 2.0 * part;
            double c = 1e-8 * F + acc[4];
            costs[p] = (c > 0.0) ? c : 0.0;
        }
    }
    __syncthreads();
    if (t == 0) {
        double dv = costs[0] - 0.5 * (costs[1] + costs[2]);
        dv = fmin(fmax(dv, 0.0), 10000.0);
        out[0] = (float)dv;
    }
}

extern "C" void kernel_launch(void* const* d_in, const int* in_sizes, int n_in,
                              void* d_out, int out_size, void* d_ws, size_t ws_size,
                              hipStream_t stream) {
    const float* X = (const float*)d_in[0];
    const float* Y = (const float*)d_in[1];
    float* out = (float*)d_out;
    char* ws = (char*)d_ws;
    float* x2 = (float*)ws;
    float* y2 = (float*)(ws + 32768);
    int* counts = (int*)(ws + 65536);
    double* accum = (double*)(ws + 65600);
    Entry* lists = (Entry*)(ws + 71936);

    init_k<<<1, 256, 0, stream>>>(counts, accum);
    norms_k<<<(2 * NROW) / 4, 256, 0, stream>>>(X, Y, x2, y2);
    prune_k<<<dim3(NROW / 128, 3), 256, 0, stream>>>(X, Y, counts, lists);
    exact_k<<<dim3(2048, 3), 256, 0, stream>>>(X, Y, x2, y2, counts, lists);
    sink_k<<<3, 1024, 0, stream>>>(X, Y, x2, y2, counts, lists, accum);
    combine_k<<<1, 64, 0, stream>>>(accum, out);
}